// Round 5
// baseline (1494.898 us; speedup 1.0000x reference)
//
#include <hip/hip_runtime.h>

typedef __bf16 bf16_t;
typedef bf16_t bf16x8 __attribute__((ext_vector_type(8)));
typedef float  f32x4  __attribute__((ext_vector_type(4)));

#define MFMA16(A, B, C) __builtin_amdgcn_mfma_f32_16x16x32_bf16((A), (B), (C), 0, 0, 0)

static constexpr int KEXT   = 288;  // 256 h | 3 x | 1 ones(bias) | 28 zero pad
static constexpr int HS     = 296;  // hx LDS row stride
static constexpr int GS     = 264;  // gate-g LDS tile stride
static constexpr int TSTEPS = 128;
static constexpr int TILE_B = 16;   // grid 256 -> 1 block/CU

// ws layout (bf16 elements)
static constexpr int WALL_OFF = 0;                    // [1152][288] gates(1024) + Wo1ext(128)
static constexpr int W2E_OFF  = 1152 * 288;           // [512][288]  encoder layer2 (+b2 col)
static constexpr int WO2E_OFF = W2E_OFF + 512 * 288;  // [16][128]   Wo2 padded
static constexpr int WS_ELEMS = WO2E_OFF + 16 * 128;

// ---------------- prep: pack weights bf16 (ws re-poisoned every launch) ----------------
__global__ __launch_bounds__(256) void prep_kernel(
    const float* __restrict__ W2,  const float* __restrict__ b2,
    const float* __restrict__ Wih, const float* __restrict__ Whh,
    const float* __restrict__ bih, const float* __restrict__ bhh,
    const float* __restrict__ Wo1, const float* __restrict__ bo1,
    const float* __restrict__ Wo2, bf16_t* __restrict__ ws)
{
    int idx = blockIdx.x * 256 + threadIdx.x;
    if (idx < 1152 * 288) {
        int r = idx / 288, k = idx - r * 288;
        float v = 0.f;
        if (r < 1024) {                       // gate rows: i f g o (256 each)
            if (k < 256)       v = Whh[r * 256 + k];
            else if (k < 259)  v = Wih[r * 3 + (k - 256)];
            else if (k == 259) v = bih[r] + bhh[r];
        } else {                              // Wo1 rows (zeros at x cols, bo1 at ones col)
            int q = r - 1024;
            if (k < 256)       v = Wo1[q * 256 + k];
            else if (k == 259) v = bo1[q];
        }
        ws[WALL_OFF + idx] = (bf16_t)v;
    } else if (idx < W2E_OFF + 512 * 288) {
        int j = idx - W2E_OFF;
        int u = j / 288, k = j - u * 288;
        float v = 0.f;
        if (k < 256)       v = W2[u * 256 + k];
        else if (k == 259) v = b2[u];
        ws[idx] = (bf16_t)v;
    } else if (idx < WS_ELEMS) {
        int j = idx - WO2E_OFF;
        int d = j >> 7, q = j & 127;
        ws[idx] = (bf16_t)((d < 3) ? Wo2[d * 128 + q] : 0.f);
    }
}

__device__ __forceinline__ float sigm(float x) { return 1.f / (1.f + __expf(-x)); }
__device__ __forceinline__ float tanh_f(float x) {
    float a = fminf(fmaxf(x, -15.f), 15.f);
    float e = __expf(2.f * a);
    return (e - 1.f) / (e + 1.f);
}
__device__ __forceinline__ unsigned pk2(float a, float b) {
    union { bf16_t h[2]; unsigned u; } x;
    x.h[0] = (bf16_t)a; x.h[1] = (bf16_t)b; return x.u;
}

// ---------------- main: 256 blocks x 512 thr (8 waves); block owns 16 batches.
// Weight placement: i,f VGPR-resident (af[2][2][9]); g LDS (wg); o + Wo1 L2-streamed.
// Streams use CONSUME-THEN-REFILL rings carried ACROSS iterations (t-invariant addrs):
//   wr : 9 slices/t, 3 slots, distance 3 (9%3==0 -> wraps cleanly across t)
//   ob : 8 slices/t (kk<8), 4 slots, distance 4 (8%4==0 -> wraps cleanly)
//   ob8: consumed in phase Y, refilled right after -> full-t slack
// Every consume has >=1 phase of slack; no phase-start load bursts (round-4 regression:
// ring fill at phase start exposed L2 latency and doubled L2 misses).
// Software-pipelined across t with 2 barriers/t:
//   ZG: z_i-GEMM + gates_{i+1} h-part (SHARED B-fragments from h_{i+1})  -> B2
//   Y : all waves redundantly y_i = z@Wo2; x_{i+1} built IN REGS; kk=8 gate slice;
//       cell update; write h_{i+2} -> B1
// Live regs ~248 of 256 VGPR+AGPR per wave @2 waves/SIMD (acc/c in AGPR): no spill.
__global__ __launch_bounds__(512, 2) void lstm_main(
    const float* __restrict__ meta, const float* __restrict__ W1,
    const float* __restrict__ b1,   const float* __restrict__ bo2,
    const bf16_t* __restrict__ ws,  float* __restrict__ out)
{
    __shared__ __align__(16) bf16_t hx[2][TILE_B][HS];  // h buffers; ext cols: [x|1|pad]
    __shared__ __align__(16) bf16_t wg[256][GS];        // gate g weights; aliased as cbuf in setup
    __shared__ __align__(16) bf16_t wo2l[16][136];
    __shared__ __align__(16) bf16_t zbuf[TILE_B][136];

    const int tid  = threadIdx.x;
    const int wv   = tid >> 6;       // 0..7
    const int lane = tid & 63;
    const int l15  = lane & 15;
    const int quad = lane >> 4;      // 0..3
    const int gb   = blockIdx.x * TILE_B;

    const bf16_t* wall = ws + WALL_OFF;
    const bf16_t* w2e  = ws + W2E_OFF;
    const bf16_t* wo2e = ws + WO2E_OFF;
    const f32x4 zero4 = {0.f, 0.f, 0.f, 0.f};

    // ---- init ext cols of both hx buffers (x0 in buf0 for prologue; ones col; zero pad) ----
    if (tid < 32) {
        int buf = tid >> 4, b = tid & 15;
        for (int c2 = 256; c2 < HS; ++c2) {
            float v = 0.f;
            if (c2 < 259)       v = buf ? 0.f : meta[(size_t)(gb + b) * 7 + (c2 - 256)];
            else if (c2 == 259) v = 1.f;
            hx[buf][b][c2] = (bf16_t)v;
        }
    }
    // ---- enc1 (VALU, K=7) into hx[1] ----
    {
        int b = tid & 15, j0 = (tid >> 4) * 8;
        float m[7];
        #pragma unroll
        for (int k = 0; k < 7; ++k) m[k] = meta[(size_t)(gb + b) * 7 + k];
        #pragma unroll
        for (int jj = 0; jj < 8; ++jj) {
            int jd = j0 + jj;
            float acc = b1[jd];
            #pragma unroll
            for (int k = 0; k < 7; ++k) acc += W1[jd * 7 + k] * m[k];
            hx[1][b][jd] = (bf16_t)fmaxf(acc, 0.f);
        }
    }
    __syncthreads();

    // ---- enc2 via MFMA: wave wv rows [64wv,64wv+64); rows<256 -> h0(hx[0]), >=256 -> c0(cbuf) ----
    float* cbuf = (float*)&wg[0][0];  // fp32 [256][17] staging inside wg space
    {
        f32x4 e[4] = {zero4, zero4, zero4, zero4};
        #pragma unroll
        for (int kk = 0; kk < 9; ++kk) {
            int ko = 32 * kk + 8 * quad;
            bf16x8 bf = *(const bf16x8*)&hx[1][l15][ko];
            #pragma unroll
            for (int m = 0; m < 4; ++m) {
                bf16x8 aa = *(const bf16x8*)&w2e[(size_t)(64 * wv + 16 * m + l15) * KEXT + ko];
                e[m] = MFMA16(aa, bf, e[m]);
            }
        }
        #pragma unroll
        for (int m = 0; m < 4; ++m) {
            int row = 64 * wv + 16 * m + 4 * quad;
            if (row < 256) {  // h0
                *(unsigned*)&hx[0][l15][row]     = pk2(fmaxf(e[m][0], 0.f), fmaxf(e[m][1], 0.f));
                *(unsigned*)&hx[0][l15][row + 2] = pk2(fmaxf(e[m][2], 0.f), fmaxf(e[m][3], 0.f));
            } else {          // c0
                int d = row - 256;
                #pragma unroll
                for (int r = 0; r < 4; ++r)
                    cbuf[(size_t)(d + r) * 17 + l15] = fmaxf(e[m][r], 0.f);
            }
        }
    }
    __syncthreads();

    // ---- c0 -> regs: c[half][r] at dim 32wv+16half+4quad+r, batch l15 ----
    f32x4 c[2];
    #pragma unroll
    for (int half = 0; half < 2; ++half)
        #pragma unroll
        for (int r = 0; r < 4; ++r)
            c[half][r] = cbuf[(size_t)(32 * wv + 16 * half + 4 * quad + r) * 17 + l15];
    __syncthreads();

    // ---- gate g -> LDS (overwrites cbuf); Wo2 -> LDS ----
    #pragma unroll
    for (int i = 0; i < 17; ++i) {
        int idx = tid + 512 * i;
        if (idx < 256 * 33) {
            int r = idx / 33, c8 = idx - r * 33;
            *(bf16x8*)&wg[r][8 * c8] = *(const bf16x8*)&wall[(size_t)(512 + r) * KEXT + 8 * c8];
        }
    }
    #pragma unroll
    for (int i = 0; i < 4; ++i) {
        int idx = tid + 512 * i;
        int r = idx >> 7, cc = idx & 127;
        wo2l[r][cc] = wo2e[r * 128 + cc];
    }

    // ---- resident A-frags: gates i,f for dims [32wv,32wv+32): af[g][half][kk] = 144 VGPR ----
    bf16x8 af[2][2][9];
    #pragma unroll
    for (int g = 0; g < 2; ++g)
        #pragma unroll
        for (int h = 0; h < 2; ++h)
            #pragma unroll
            for (int kk = 0; kk < 9; ++kk)
                af[g][h][kk] = *(const bf16x8*)&wall[(size_t)(256 * g + 32 * wv + 16 * h + l15) * KEXT
                                                     + 32 * kk + 8 * quad];

    // ---- stream bases (t-invariant addresses) ----
    const bf16_t* obase = wall + (size_t)(768  + 32 * wv + l15) * KEXT + 8 * quad;  // gate o
    const bf16_t* wbase = wall + (size_t)(1024 + 16 * wv + l15) * KEXT + 8 * quad;  // Wo1

    const float bo2v0 = bo2[0], bo2v1 = bo2[1], bo2v2 = bo2[2];

    // steady-state rings (carried across iterations)
    bf16x8 wr[3], ob[4][2], ob8[2];

    __syncthreads();   // wg/wo2l ready

    // ---- prologue: gates_0 (full kk0..8; x_0 from hx[0] ext cols), cell -> c_1, h_1 -> hx[1].
    //      Uses its own local ring (pob, load-before-consume, dist 3 / 4 slots). ----
    {
        f32x4 acc[4][2];
        #pragma unroll
        for (int g = 0; g < 4; ++g) { acc[g][0] = zero4; acc[g][1] = zero4; }
        bf16x8 pob[4][2];
        #pragma unroll
        for (int s = 0; s < 3; ++s)
            #pragma unroll
            for (int h = 0; h < 2; ++h)
                pob[s][h] = *(const bf16x8*)(obase + (size_t)(16 * h) * KEXT + 32 * s);
        #pragma unroll
        for (int kk = 0; kk < 9; ++kk) {
            int ko = 32 * kk + 8 * quad;
            bf16x8 bf = *(const bf16x8*)&hx[0][l15][ko];
            if (kk + 3 <= 8) {
                #pragma unroll
                for (int h = 0; h < 2; ++h)
                    pob[(kk + 3) & 3][h] = *(const bf16x8*)(obase + (size_t)(16 * h) * KEXT
                                                            + 32 * (kk + 3));
            }
            #pragma unroll
            for (int h = 0; h < 2; ++h) {
                bf16x8 ag = *(const bf16x8*)&wg[32 * wv + 16 * h + l15][ko];
                acc[0][h] = MFMA16(af[0][h][kk], bf, acc[0][h]);
                acc[1][h] = MFMA16(af[1][h][kk], bf, acc[1][h]);
                acc[2][h] = MFMA16(ag,             bf, acc[2][h]);
                acc[3][h] = MFMA16(pob[kk & 3][h], bf, acc[3][h]);
            }
        }
        // fill steady-state rings now: slack = cell VALU + barrier before first consume (ZG0),
        // a full ZG phase before ob8's first consume (Y0). All lines L2-hot from prologue.
        #pragma unroll
        for (int s = 0; s < 3; ++s)
            wr[s] = *(const bf16x8*)(wbase + 32 * s);
        #pragma unroll
        for (int s = 0; s < 4; ++s)
            #pragma unroll
            for (int h = 0; h < 2; ++h)
                ob[s][h] = *(const bf16x8*)(obase + (size_t)(16 * h) * KEXT + 32 * s);
        #pragma unroll
        for (int h = 0; h < 2; ++h)
            ob8[h] = *(const bf16x8*)(obase + (size_t)(16 * h) * KEXT + 256);

        #pragma unroll
        for (int half = 0; half < 2; ++half) {
            float hh[4];
            #pragma unroll
            for (int r = 0; r < 4; ++r) {
                float iv = acc[0][half][r], fv = acc[1][half][r];
                float gv = acc[2][half][r], ov = acc[3][half][r];
                float cc = sigm(fv) * c[half][r] + sigm(iv) * tanh_f(gv);
                c[half][r] = cc;
                hh[r] = sigm(ov) * tanh_f(cc);
            }
            int dim = 32 * wv + 16 * half + 4 * quad;
            *(unsigned*)&hx[1][l15][dim]     = pk2(hh[0], hh[1]);
            *(unsigned*)&hx[1][l15][dim + 2] = pk2(hh[2], hh[3]);
        }
    }
    __syncthreads();   // h_1 visible

    // ================= time loop: iter i emits y_i, computes gates_{i+1} & h_{i+2} =========
    for (int i = 0; i < TSTEPS; ++i) {
        const bf16_t (*cur)[HS] = hx[(i + 1) & 1];   // h_{i+1}
        bf16_t (*nxt)[HS]       = hx[i & 1];         // h_{i+2} destination

        // -- phase ZG: z_i = relu(h@Wo1^T) AND gates_{i+1} h-part (kk0..7), shared bf --
        f32x4 acc[4][2];
        #pragma unroll
        for (int g = 0; g < 4; ++g) { acc[g][0] = zero4; acc[g][1] = zero4; }
        f32x4 zacc = zero4;

        #pragma unroll
        for (int kk = 0; kk < 9; ++kk) {
            int ko = 32 * kk + 8 * quad;
            bf16x8 bf = *(const bf16x8*)&cur[l15][ko];
            // consume wr slot, then refill it with slice (kk+3)%9 (WAR orders load after MFMA)
            zacc = MFMA16(wr[kk % 3], bf, zacc);   // ext cols: x*0 (Wo1ext=0), ones*bo1
            wr[kk % 3] = *(const bf16x8*)(wbase + 32 * ((kk + 3) % 9));
            if (kk < 8) {
                #pragma unroll
                for (int h = 0; h < 2; ++h) {
                    bf16x8 ag = *(const bf16x8*)&wg[32 * wv + 16 * h + l15][ko];
                    acc[0][h] = MFMA16(af[0][h][kk], bf, acc[0][h]);
                    acc[1][h] = MFMA16(af[1][h][kk], bf, acc[1][h]);
                    acc[2][h] = MFMA16(ag,            bf, acc[2][h]);
                    acc[3][h] = MFMA16(ob[kk & 3][h], bf, acc[3][h]);
                }
                // refill consumed ob slot with slice (kk+4)&7
                #pragma unroll
                for (int h = 0; h < 2; ++h)
                    ob[kk & 3][h] = *(const bf16x8*)(obase + (size_t)(16 * h) * KEXT
                                                     + 32 * ((kk + 4) & 7));
            }
        }
        {
            int zd = 16 * wv + 4 * quad;
            *(unsigned*)&zbuf[l15][zd]     = pk2(fmaxf(zacc[0], 0.f), fmaxf(zacc[1], 0.f));
            *(unsigned*)&zbuf[l15][zd + 2] = pk2(fmaxf(zacc[2], 0.f), fmaxf(zacc[3], 0.f));
        }
        __syncthreads();   // B2: z complete

        // -- phase Y: ALL waves y_i = z@Wo2^T (redundant, identical); x_{i+1} in regs;
        //             kk=8 gate slice; cell update; write h_{i+2} --
        {
            f32x4 ya = zero4;
            #pragma unroll
            for (int kk = 0; kk < 4; ++kk) {
                int ko = 32 * kk + 8 * quad;
                ya = MFMA16(*(const bf16x8*)&wo2l[l15][ko],
                            *(const bf16x8*)&zbuf[l15][ko], ya);
            }
            float y0 = ya[0] + bo2v0, y1 = ya[1] + bo2v1, y2 = ya[2] + bo2v2;
            if (wv == (i & 7) && quad == 0) {   // rotate storer: ack hides under cell VALU
                float* op = out + ((size_t)(gb + l15) * TSTEPS + i) * 3;
                op[0] = y0; op[1] = y1; op[2] = y2;
            }
            // x_{i+1} fragment in regs: quad0 = {y0,y1,y2,1,0,0,0,0}, quads 1..3 = 0
            bf16x8 xf;
            #pragma unroll
            for (int j = 0; j < 8; ++j) xf[j] = (bf16_t)0.f;
            if (quad == 0) {
                xf[0] = (bf16_t)y0; xf[1] = (bf16_t)y1; xf[2] = (bf16_t)y2; xf[3] = (bf16_t)1.f;
            }
            // kk=8 gate slice (A-frag garbage beyond col 263 is multiplied by zero B)
            #pragma unroll
            for (int h = 0; h < 2; ++h) {
                bf16x8 ag8 = *(const bf16x8*)&wg[32 * wv + 16 * h + l15][256 + 8 * quad];
                acc[0][h] = MFMA16(af[0][h][8], xf, acc[0][h]);
                acc[1][h] = MFMA16(af[1][h][8], xf, acc[1][h]);
                acc[2][h] = MFMA16(ag8,         xf, acc[2][h]);
                acc[3][h] = MFMA16(ob8[h],      xf, acc[3][h]);
            }
            // refill ob8 (consumed above) -> full timestep of slack
            #pragma unroll
            for (int h = 0; h < 2; ++h)
                ob8[h] = *(const bf16x8*)(obase + (size_t)(16 * h) * KEXT + 256);
            #pragma unroll
            for (int half = 0; half < 2; ++half) {
                float hh[4];
                #pragma unroll
                for (int r = 0; r < 4; ++r) {
                    float iv = acc[0][half][r], fv = acc[1][half][r];
                    float gv = acc[2][half][r], ov = acc[3][half][r];
                    float cc = sigm(fv) * c[half][r] + sigm(iv) * tanh_f(gv);
                    c[half][r] = cc;
                    hh[r] = sigm(ov) * tanh_f(cc);
                }
                int dim = 32 * wv + 16 * half + 4 * quad;
                *(unsigned*)&nxt[l15][dim]     = pk2(hh[0], hh[1]);
                *(unsigned*)&nxt[l15][dim + 2] = pk2(hh[2], hh[3]);
            }
        }
        __syncthreads();   // B1: h_{i+2} visible
    }
}

extern "C" void kernel_launch(void* const* d_in, const int* in_sizes, int n_in,
                              void* d_out, int out_size, void* d_ws, size_t ws_size,
                              hipStream_t stream)
{
    const float* meta = (const float*)d_in[0];
    const float* W1   = (const float*)d_in[2];
    const float* b1   = (const float*)d_in[3];
    const float* W2   = (const float*)d_in[4];
    const float* b2   = (const float*)d_in[5];
    const float* Wih  = (const float*)d_in[6];
    const float* Whh  = (const float*)d_in[7];
    const float* bih  = (const float*)d_in[8];
    const float* bhh  = (const float*)d_in[9];
    const float* Wo1  = (const float*)d_in[10];
    const float* bo1  = (const float*)d_in[11];
    const float* Wo2  = (const float*)d_in[12];
    const float* bo2  = (const float*)d_in[13];
    bf16_t* ws  = (bf16_t*)d_ws;
    float*  out = (float*)d_out;

    prep_kernel<<<dim3((WS_ELEMS + 255) / 256), dim3(256), 0, stream>>>(
        W2, b2, Wih, Whh, bih, bhh, Wo1, bo1, Wo2, ws);
    lstm_main<<<dim3(4096 / TILE_B), dim3(512), 0, stream>>>(
        meta, W1, b1, bo2, ws, out);
}

// Round 6
// 1331.559 us; speedup vs baseline: 1.1227x; 1.1227x over previous
//
#include <hip/hip_runtime.h>

typedef __bf16 bf16_t;
typedef bf16_t bf16x8 __attribute__((ext_vector_type(8)));
typedef float  f32x4  __attribute__((ext_vector_type(4)));

#define MFMA16(A, B, C) __builtin_amdgcn_mfma_f32_16x16x32_bf16((A), (B), (C), 0, 0, 0)

static constexpr int KEXT   = 288;  // 256 h | 3 x | 1 ones(bias) | 28 zero pad
static constexpr int HS     = 296;  // hx LDS row stride
static constexpr int GS     = 264;  // gate-g LDS tile stride
static constexpr int TSTEPS = 128;
static constexpr int TILE_B = 16;   // grid 256 -> 1 block/CU

// ws layout (bf16 elements)
static constexpr int WALL_OFF = 0;                    // [1152][288] gates(1024) + Wo1ext(128)
static constexpr int W2E_OFF  = 1152 * 288;           // [512][288]  encoder layer2 (+b2 col)
static constexpr int WO2E_OFF = W2E_OFF + 512 * 288;  // [16][128]   Wo2 padded
static constexpr int WS_ELEMS = WO2E_OFF + 16 * 128;

// ---------------- prep: pack weights bf16 (ws re-poisoned every launch) ----------------
__global__ __launch_bounds__(256) void prep_kernel(
    const float* __restrict__ W2,  const float* __restrict__ b2,
    const float* __restrict__ Wih, const float* __restrict__ Whh,
    const float* __restrict__ bih, const float* __restrict__ bhh,
    const float* __restrict__ Wo1, const float* __restrict__ bo1,
    const float* __restrict__ Wo2, bf16_t* __restrict__ ws)
{
    int idx = blockIdx.x * 256 + threadIdx.x;
    if (idx < 1152 * 288) {
        int r = idx / 288, k = idx - r * 288;
        float v = 0.f;
        if (r < 1024) {                       // gate rows: i f g o (256 each)
            if (k < 256)       v = Whh[r * 256 + k];
            else if (k < 259)  v = Wih[r * 3 + (k - 256)];
            else if (k == 259) v = bih[r] + bhh[r];
        } else {                              // Wo1 rows (zeros at x cols, bo1 at ones col)
            int q = r - 1024;
            if (k < 256)       v = Wo1[q * 256 + k];
            else if (k == 259) v = bo1[q];
        }
        ws[WALL_OFF + idx] = (bf16_t)v;
    } else if (idx < W2E_OFF + 512 * 288) {
        int j = idx - W2E_OFF;
        int u = j / 288, k = j - u * 288;
        float v = 0.f;
        if (k < 256)       v = W2[u * 256 + k];
        else if (k == 259) v = b2[u];
        ws[idx] = (bf16_t)v;
    } else if (idx < WS_ELEMS) {
        int j = idx - WO2E_OFF;
        int d = j >> 7, q = j & 127;
        ws[idx] = (bf16_t)((d < 3) ? Wo2[d * 128 + q] : 0.f);
    }
}

__device__ __forceinline__ float sigm(float x) { return 1.f / (1.f + __expf(-x)); }
__device__ __forceinline__ float tanh_f(float x) {
    float a = fminf(fmaxf(x, -15.f), 15.f);
    float e = __expf(2.f * a);
    return (e - 1.f) / (e + 1.f);
}
__device__ __forceinline__ unsigned pk2(float a, float b) {
    union { bf16_t h[2]; unsigned u; } x;
    x.h[0] = (bf16_t)a; x.h[1] = (bf16_t)b; return x.u;
}

// Raw barrier: LDS visibility only (lgkmcnt drain), NO vmcnt drain -> global prefetches
// stay in flight across phases (the guide's verified 8-phase-template idiom).
// __syncthreads would emit s_waitcnt vmcnt(0) and kill every cross-phase prefetch.
__device__ __forceinline__ void bar_lds() {
    asm volatile("s_waitcnt lgkmcnt(0)" ::: "memory");
    __builtin_amdgcn_s_barrier();
}

// ---------------- main: 256 blocks x 512 thr (8 waves); block owns 16 batches.
// Weight placement: i,f VGPR-resident (af[2][2][9]); g LDS (wg); o + Wo1 L2-streamed.
// Stream schedule (R2's empirically-clean pattern, distance-2 DISTINCT slots):
//   wr: consume slot kk%3 (slice kk), load slice (kk+2)%9 -> slot (kk+2)%3  (9%3==0 wraps)
//   ob: consume slot kk&3 (slice kk, kk<8), load slice (kk+2)&7 -> slot (kk+2)&3 (8%4==0)
//   ob8 (o-gate x-slice): transient reload at Y start (L1/L2-hot constant address)
// With raw barriers the kk=6,7,8 wrap loads survive B2+B1 -> slices 0,1 consumed next-t
// have a full phase-pair of slack; in-phase consumes have ~2-iteration slack + 2-wave TLP.
// 2 barriers/t: ZG (z_i + gates_{i+1} h-part, shared B-frags) -> B2 -> Y (redundant y,
// x in regs, kk=8 slice, cell, h_{i+2}) -> B1.
// Steady live regs ~250 of 256 VGPR+AGPR cap @2 waves/SIMD.
__global__ __launch_bounds__(512, 2) void lstm_main(
    const float* __restrict__ meta, const float* __restrict__ W1,
    const float* __restrict__ b1,   const float* __restrict__ bo2,
    const bf16_t* __restrict__ ws,  float* __restrict__ out)
{
    __shared__ __align__(16) bf16_t hx[2][TILE_B][HS];  // h buffers; ext cols: [x|1|pad]
    __shared__ __align__(16) bf16_t wg[256][GS];        // gate g weights; aliased as cbuf in setup
    __shared__ __align__(16) bf16_t wo2l[16][136];
    __shared__ __align__(16) bf16_t zbuf[TILE_B][136];

    const int tid  = threadIdx.x;
    const int wv   = tid >> 6;       // 0..7
    const int lane = tid & 63;
    const int l15  = lane & 15;
    const int quad = lane >> 4;      // 0..3
    const int gb   = blockIdx.x * TILE_B;

    const bf16_t* wall = ws + WALL_OFF;
    const bf16_t* w2e  = ws + W2E_OFF;
    const bf16_t* wo2e = ws + WO2E_OFF;
    const f32x4 zero4 = {0.f, 0.f, 0.f, 0.f};

    // ---- init ext cols of both hx buffers (x0 in buf0 for prologue; ones col; zero pad) ----
    if (tid < 32) {
        int buf = tid >> 4, b = tid & 15;
        for (int c2 = 256; c2 < HS; ++c2) {
            float v = 0.f;
            if (c2 < 259)       v = buf ? 0.f : meta[(size_t)(gb + b) * 7 + (c2 - 256)];
            else if (c2 == 259) v = 1.f;
            hx[buf][b][c2] = (bf16_t)v;
        }
    }
    // ---- enc1 (VALU, K=7) into hx[1] ----
    {
        int b = tid & 15, j0 = (tid >> 4) * 8;
        float m[7];
        #pragma unroll
        for (int k = 0; k < 7; ++k) m[k] = meta[(size_t)(gb + b) * 7 + k];
        #pragma unroll
        for (int jj = 0; jj < 8; ++jj) {
            int jd = j0 + jj;
            float acc = b1[jd];
            #pragma unroll
            for (int k = 0; k < 7; ++k) acc += W1[jd * 7 + k] * m[k];
            hx[1][b][jd] = (bf16_t)fmaxf(acc, 0.f);
        }
    }
    __syncthreads();

    // ---- enc2 via MFMA: wave wv rows [64wv,64wv+64); rows<256 -> h0(hx[0]), >=256 -> c0(cbuf) ----
    float* cbuf = (float*)&wg[0][0];  // fp32 [256][17] staging inside wg space
    {
        f32x4 e[4] = {zero4, zero4, zero4, zero4};
        #pragma unroll
        for (int kk = 0; kk < 9; ++kk) {
            int ko = 32 * kk + 8 * quad;
            bf16x8 bf = *(const bf16x8*)&hx[1][l15][ko];
            #pragma unroll
            for (int m = 0; m < 4; ++m) {
                bf16x8 aa = *(const bf16x8*)&w2e[(size_t)(64 * wv + 16 * m + l15) * KEXT + ko];
                e[m] = MFMA16(aa, bf, e[m]);
            }
        }
        #pragma unroll
        for (int m = 0; m < 4; ++m) {
            int row = 64 * wv + 16 * m + 4 * quad;
            if (row < 256) {  // h0
                *(unsigned*)&hx[0][l15][row]     = pk2(fmaxf(e[m][0], 0.f), fmaxf(e[m][1], 0.f));
                *(unsigned*)&hx[0][l15][row + 2] = pk2(fmaxf(e[m][2], 0.f), fmaxf(e[m][3], 0.f));
            } else {          // c0
                int d = row - 256;
                #pragma unroll
                for (int r = 0; r < 4; ++r)
                    cbuf[(size_t)(d + r) * 17 + l15] = fmaxf(e[m][r], 0.f);
            }
        }
    }
    __syncthreads();

    // ---- c0 -> regs: c[half][r] at dim 32wv+16half+4quad+r, batch l15 ----
    f32x4 c[2];
    #pragma unroll
    for (int half = 0; half < 2; ++half)
        #pragma unroll
        for (int r = 0; r < 4; ++r)
            c[half][r] = cbuf[(size_t)(32 * wv + 16 * half + 4 * quad + r) * 17 + l15];
    __syncthreads();

    // ---- gate g -> LDS (overwrites cbuf); Wo2 -> LDS ----
    #pragma unroll
    for (int i = 0; i < 17; ++i) {
        int idx = tid + 512 * i;
        if (idx < 256 * 33) {
            int r = idx / 33, c8 = idx - r * 33;
            *(bf16x8*)&wg[r][8 * c8] = *(const bf16x8*)&wall[(size_t)(512 + r) * KEXT + 8 * c8];
        }
    }
    #pragma unroll
    for (int i = 0; i < 4; ++i) {
        int idx = tid + 512 * i;
        int r = idx >> 7, cc = idx & 127;
        wo2l[r][cc] = wo2e[r * 128 + cc];
    }

    // ---- resident A-frags: gates i,f for dims [32wv,32wv+32): af[g][half][kk] = 144 VGPR ----
    bf16x8 af[2][2][9];
    #pragma unroll
    for (int g = 0; g < 2; ++g)
        #pragma unroll
        for (int h = 0; h < 2; ++h)
            #pragma unroll
            for (int kk = 0; kk < 9; ++kk)
                af[g][h][kk] = *(const bf16x8*)&wall[(size_t)(256 * g + 32 * wv + 16 * h + l15) * KEXT
                                                     + 32 * kk + 8 * quad];

    // ---- stream bases (t-invariant addresses) ----
    const bf16_t* obase = wall + (size_t)(768  + 32 * wv + l15) * KEXT + 8 * quad;  // gate o
    const bf16_t* wbase = wall + (size_t)(1024 + 16 * wv + l15) * KEXT + 8 * quad;  // Wo1

    const float bo2v0 = bo2[0], bo2v1 = bo2[1], bo2v2 = bo2[2];

    // steady-state rings (carried across iterations)
    bf16x8 wr[3], ob[4][2];

    __syncthreads();   // wg/wo2l ready

    // ---- prologue: gates_0 (full kk0..8; x_0 from hx[0] ext cols), cell -> c_1, h_1 -> hx[1].
    //      One-time: o-gate loaded directly per kk (exposed latency, irrelevant). ----
    {
        f32x4 acc[4][2];
        #pragma unroll
        for (int g = 0; g < 4; ++g) { acc[g][0] = zero4; acc[g][1] = zero4; }
        #pragma unroll
        for (int kk = 0; kk < 9; ++kk) {
            int ko = 32 * kk + 8 * quad;
            bf16x8 po0 = *(const bf16x8*)(obase + 32 * kk);
            bf16x8 po1 = *(const bf16x8*)(obase + (size_t)16 * KEXT + 32 * kk);
            bf16x8 bf  = *(const bf16x8*)&hx[0][l15][ko];
            #pragma unroll
            for (int h = 0; h < 2; ++h) {
                bf16x8 ag = *(const bf16x8*)&wg[32 * wv + 16 * h + l15][ko];
                acc[0][h] = MFMA16(af[0][h][kk], bf, acc[0][h]);
                acc[1][h] = MFMA16(af[1][h][kk], bf, acc[1][h]);
                acc[2][h] = MFMA16(ag,           bf, acc[2][h]);
                acc[3][h] = MFMA16(h ? po1 : po0, bf, acc[3][h]);
            }
        }
        // fill steady rings: slices 0,1 (slot 2 / slots 2,3 get loaded at kk=0,1 of ZG0)
        #pragma unroll
        for (int s = 0; s < 2; ++s) {
            wr[s] = *(const bf16x8*)(wbase + 32 * s);
            #pragma unroll
            for (int h = 0; h < 2; ++h)
                ob[s][h] = *(const bf16x8*)(obase + (size_t)(16 * h) * KEXT + 32 * s);
        }
        #pragma unroll
        for (int half = 0; half < 2; ++half) {
            float hh[4];
            #pragma unroll
            for (int r = 0; r < 4; ++r) {
                float iv = acc[0][half][r], fv = acc[1][half][r];
                float gv = acc[2][half][r], ov = acc[3][half][r];
                float cc = sigm(fv) * c[half][r] + sigm(iv) * tanh_f(gv);
                c[half][r] = cc;
                hh[r] = sigm(ov) * tanh_f(cc);
            }
            int dim = 32 * wv + 16 * half + 4 * quad;
            *(unsigned*)&hx[1][l15][dim]     = pk2(hh[0], hh[1]);
            *(unsigned*)&hx[1][l15][dim + 2] = pk2(hh[2], hh[3]);
        }
    }
    bar_lds();   // h_1 visible; ring prefetches stay in flight

    // ================= time loop: iter i emits y_i, computes gates_{i+1} & h_{i+2} =========
    for (int i = 0; i < TSTEPS; ++i) {
        const bf16_t (*cur)[HS] = hx[(i + 1) & 1];   // h_{i+1}
        bf16_t (*nxt)[HS]       = hx[i & 1];         // h_{i+2} destination

        // -- phase ZG: z_i = relu(h@Wo1^T) AND gates_{i+1} h-part (kk0..7), shared bf --
        f32x4 acc[4][2];
        #pragma unroll
        for (int g = 0; g < 4; ++g) { acc[g][0] = zero4; acc[g][1] = zero4; }
        f32x4 zacc = zero4;

        #pragma unroll
        for (int kk = 0; kk < 9; ++kk) {
            int ko = 32 * kk + 8 * quad;
            bf16x8 bf = *(const bf16x8*)&cur[l15][ko];
            zacc = MFMA16(wr[kk % 3], bf, zacc);   // ext cols: x*0 (Wo1ext=0), ones*bo1
            wr[(kk + 2) % 3] = *(const bf16x8*)(wbase + 32 * ((kk + 2) % 9));
            if (kk < 8) {
                #pragma unroll
                for (int h = 0; h < 2; ++h) {
                    bf16x8 ag = *(const bf16x8*)&wg[32 * wv + 16 * h + l15][ko];
                    acc[0][h] = MFMA16(af[0][h][kk], bf, acc[0][h]);
                    acc[1][h] = MFMA16(af[1][h][kk], bf, acc[1][h]);
                    acc[2][h] = MFMA16(ag,            bf, acc[2][h]);
                    acc[3][h] = MFMA16(ob[kk & 3][h], bf, acc[3][h]);
                }
                #pragma unroll
                for (int h = 0; h < 2; ++h)
                    ob[(kk + 2) & 3][h] = *(const bf16x8*)(obase + (size_t)(16 * h) * KEXT
                                                           + 32 * ((kk + 2) & 7));
            }
        }
        {
            int zd = 16 * wv + 4 * quad;
            *(unsigned*)&zbuf[l15][zd]     = pk2(fmaxf(zacc[0], 0.f), fmaxf(zacc[1], 0.f));
            *(unsigned*)&zbuf[l15][zd + 2] = pk2(fmaxf(zacc[2], 0.f), fmaxf(zacc[3], 0.f));
        }
        bar_lds();   // B2: z complete; wrap prefetches (slices 0,1 of t+1) stay in flight

        // -- phase Y: ALL waves y_i = z@Wo2^T (redundant, identical); x_{i+1} in regs;
        //             kk=8 gate slice; cell update; write h_{i+2} --
        {
            bf16x8 ob8[2];   // o-gate x-slice: transient reload (constant addr, L1/L2-hot)
            #pragma unroll
            for (int h = 0; h < 2; ++h)
                ob8[h] = *(const bf16x8*)(obase + (size_t)(16 * h) * KEXT + 256);
            f32x4 ya = zero4;
            #pragma unroll
            for (int kk = 0; kk < 4; ++kk) {
                int ko = 32 * kk + 8 * quad;
                ya = MFMA16(*(const bf16x8*)&wo2l[l15][ko],
                            *(const bf16x8*)&zbuf[l15][ko], ya);
            }
            float y0 = ya[0] + bo2v0, y1 = ya[1] + bo2v1, y2 = ya[2] + bo2v2;
            if (wv == (i & 7) && quad == 0) {   // rotate storer: ack hides under cell VALU
                float* op = out + ((size_t)(gb + l15) * TSTEPS + i) * 3;
                op[0] = y0; op[1] = y1; op[2] = y2;
            }
            // x_{i+1} fragment in regs: quad0 = {y0,y1,y2,1,0,0,0,0}, quads 1..3 = 0
            bf16x8 xf;
            #pragma unroll
            for (int j = 0; j < 8; ++j) xf[j] = (bf16_t)0.f;
            if (quad == 0) {
                xf[0] = (bf16_t)y0; xf[1] = (bf16_t)y1; xf[2] = (bf16_t)y2; xf[3] = (bf16_t)1.f;
            }
            // kk=8 gate slice (A-frag garbage beyond col 263 is multiplied by zero B)
            #pragma unroll
            for (int h = 0; h < 2; ++h) {
                bf16x8 ag8 = *(const bf16x8*)&wg[32 * wv + 16 * h + l15][256 + 8 * quad];
                acc[0][h] = MFMA16(af[0][h][8], xf, acc[0][h]);
                acc[1][h] = MFMA16(af[1][h][8], xf, acc[1][h]);
                acc[2][h] = MFMA16(ag8,         xf, acc[2][h]);
                acc[3][h] = MFMA16(ob8[h],      xf, acc[3][h]);
            }
            #pragma unroll
            for (int half = 0; half < 2; ++half) {
                float hh[4];
                #pragma unroll
                for (int r = 0; r < 4; ++r) {
                    float iv = acc[0][half][r], fv = acc[1][half][r];
                    float gv = acc[2][half][r], ov = acc[3][half][r];
                    float cc = sigm(fv) * c[half][r] + sigm(iv) * tanh_f(gv);
                    c[half][r] = cc;
                    hh[r] = sigm(ov) * tanh_f(cc);
                }
                int dim = 32 * wv + 16 * half + 4 * quad;
                *(unsigned*)&nxt[l15][dim]     = pk2(hh[0], hh[1]);
                *(unsigned*)&nxt[l15][dim + 2] = pk2(hh[2], hh[3]);
            }
        }
        bar_lds();   // B1: h_{i+2} visible; wrap prefetches stay in flight
    }
}

extern "C" void kernel_launch(void* const* d_in, const int* in_sizes, int n_in,
                              void* d_out, int out_size, void* d_ws, size_t ws_size,
                              hipStream_t stream)
{
    const float* meta = (const float*)d_in[0];
    const float* W1   = (const float*)d_in[2];
    const float* b1   = (const float*)d_in[3];
    const float* W2   = (const float*)d_in[4];
    const float* b2   = (const float*)d_in[5];
    const float* Wih  = (const float*)d_in[6];
    const float* Whh  = (const float*)d_in[7];
    const float* bih  = (const float*)d_in[8];
    const float* bhh  = (const float*)d_in[9];
    const float* Wo1  = (const float*)d_in[10];
    const float* bo1  = (const float*)d_in[11];
    const float* Wo2  = (const float*)d_in[12];
    const float* bo2  = (const float*)d_in[13];
    bf16_t* ws  = (bf16_t*)d_ws;
    float*  out = (float*)d_out;

    prep_kernel<<<dim3((WS_ELEMS + 255) / 256), dim3(256), 0, stream>>>(
        W2, b2, Wih, Whh, bih, bhh, Wo1, bo1, Wo2, ws);
    lstm_main<<<dim3(4096 / TILE_B), dim3(512), 0, stream>>>(
        meta, W1, b1, bo2, ws, out);
}

// Round 7
// 919.119 us; speedup vs baseline: 1.6264x; 1.4487x over previous
//
#include <hip/hip_runtime.h>

typedef __bf16 bf16_t;
typedef bf16_t bf16x8 __attribute__((ext_vector_type(8)));
typedef float  f32x4  __attribute__((ext_vector_type(4)));

#define MFMA16(A, B, C) __builtin_amdgcn_mfma_f32_16x16x32_bf16((A), (B), (C), 0, 0, 0)

static constexpr int KEXT   = 288;  // 256 h | 3 x | 1 ones(bias) | 28 zero pad
static constexpr int HS     = 296;  // hx LDS row stride
static constexpr int GS     = 264;  // gate-g LDS tile stride
static constexpr int TSTEPS = 128;
static constexpr int TILE_B = 16;   // grid 256 -> 1 block/CU

// ws layout (bf16 elements)
static constexpr int WALL_OFF = 0;                    // [1152][288] gates(1024) + Wo1ext(128)
static constexpr int W2E_OFF  = 1152 * 288;           // [512][288]  encoder layer2 (+b2 col)
static constexpr int WO2E_OFF = W2E_OFF + 512 * 288;  // [16][128]   Wo2 padded
static constexpr int WS_ELEMS = WO2E_OFF + 16 * 128;

// ---------------- prep: pack weights bf16 (ws re-poisoned every launch) ----------------
__global__ __launch_bounds__(256) void prep_kernel(
    const float* __restrict__ W2,  const float* __restrict__ b2,
    const float* __restrict__ Wih, const float* __restrict__ Whh,
    const float* __restrict__ bih, const float* __restrict__ bhh,
    const float* __restrict__ Wo1, const float* __restrict__ bo1,
    const float* __restrict__ Wo2, bf16_t* __restrict__ ws)
{
    int idx = blockIdx.x * 256 + threadIdx.x;
    if (idx < 1152 * 288) {
        int r = idx / 288, k = idx - r * 288;
        float v = 0.f;
        if (r < 1024) {                       // gate rows: i f g o (256 each)
            if (k < 256)       v = Whh[r * 256 + k];
            else if (k < 259)  v = Wih[r * 3 + (k - 256)];
            else if (k == 259) v = bih[r] + bhh[r];
        } else {                              // Wo1 rows (zeros at x cols, bo1 at ones col)
            int q = r - 1024;
            if (k < 256)       v = Wo1[q * 256 + k];
            else if (k == 259) v = bo1[q];
        }
        ws[WALL_OFF + idx] = (bf16_t)v;
    } else if (idx < W2E_OFF + 512 * 288) {
        int j = idx - W2E_OFF;
        int u = j / 288, k = j - u * 288;
        float v = 0.f;
        if (k < 256)       v = W2[u * 256 + k];
        else if (k == 259) v = b2[u];
        ws[idx] = (bf16_t)v;
    } else if (idx < WS_ELEMS) {
        int j = idx - WO2E_OFF;
        int d = j >> 7, q = j & 127;
        ws[idx] = (bf16_t)((d < 3) ? Wo2[d * 128 + q] : 0.f);
    }
}

__device__ __forceinline__ float sigm(float x) { return 1.f / (1.f + __expf(-x)); }
__device__ __forceinline__ float tanh_f(float x) {
    float a = fminf(fmaxf(x, -15.f), 15.f);
    float e = __expf(2.f * a);
    return (e - 1.f) / (e + 1.f);
}
__device__ __forceinline__ unsigned pk2(float a, float b) {
    union { bf16_t h[2]; unsigned u; } x;
    x.h[0] = (bf16_t)a; x.h[1] = (bf16_t)b; return x.u;
}

// Raw barrier: LDS visibility only (lgkmcnt drain), NO vmcnt drain -> the rings' carried
// wrap prefetches (issued at kk=7,8) survive the barrier instead of being force-drained.
__device__ __forceinline__ void bar_lds() {
    asm volatile("s_waitcnt lgkmcnt(0)" ::: "memory");
    __builtin_amdgcn_s_barrier();
}

// ---------------- main: 256 blocks x 512 thr (8 waves); block owns 16 batches.
// EXACTLY round-2's weight placement and stream schedule (the empirical FETCH minimum):
//   i,f : VGPR-resident af[2][2][9] (144 VGPR)
//   g   : LDS-resident wg[256][264]
//   o   : 9-slice stream, 3-slot ring, distance-2 carried wrap:
//         consume ob[kk%3] (slice kk), load slice (kk+2)%9 -> slot (kk+2)%3
//   Wo1 : 9-slice stream, identical 3-slot carried ring in the Z phase
// Structural changes vs round-2 (scheduling untouched):
//   * raw lgkmcnt barriers (vmcnt stays in flight across phases)
//   * phase-4 (serial wave0 y + x->LDS + B3) replaced by redundant all-wave y with the
//     x_{t+1} fragment kept IN REGISTERS (xf); G-phase kk=8 consumes xf directly.
//     2 barriers/t, no serial tail. Y->G needs no barrier: Y touches only zbuf/wo2l;
//     G reads the opposite hx buffer from the one its cell writes; B1/B2 cover the rest.
__global__ __launch_bounds__(512, 2) void lstm_main(
    const float* __restrict__ meta, const float* __restrict__ W1,
    const float* __restrict__ b1,   const float* __restrict__ bo2,
    const bf16_t* __restrict__ ws,  float* __restrict__ out)
{
    __shared__ __align__(16) bf16_t hx[2][TILE_B][HS];  // h buffers; ext cols [0,0,0,1,pad]
    __shared__ __align__(16) bf16_t wg[256][GS];        // gate g weights; aliased as cbuf in setup
    __shared__ __align__(16) bf16_t wo2l[16][136];
    __shared__ __align__(16) bf16_t zbuf[TILE_B][136];

    const int tid  = threadIdx.x;
    const int wv   = tid >> 6;       // 0..7
    const int lane = tid & 63;
    const int l15  = lane & 15;
    const int quad = lane >> 4;      // 0..3
    const int gb   = blockIdx.x * TILE_B;

    const bf16_t* wall = ws + WALL_OFF;
    const bf16_t* w2e  = ws + W2E_OFF;
    const bf16_t* wo2e = ws + WO2E_OFF;
    const f32x4 zero4 = {0.f, 0.f, 0.f, 0.f};

    // ---- init ext cols of both hx buffers: zeros, ones col (z-bias via Wo1ext) ----
    if (tid < 32) {
        int buf = tid >> 4, b = tid & 15;
        for (int c2 = 256; c2 < HS; ++c2)
            hx[buf][b][c2] = (bf16_t)((c2 == 259) ? 1.f : 0.f);
    }
    // ---- enc1 (VALU, K=7) into hx[1] ----
    {
        int b = tid & 15, j0 = (tid >> 4) * 8;
        float m[7];
        #pragma unroll
        for (int k = 0; k < 7; ++k) m[k] = meta[(size_t)(gb + b) * 7 + k];
        #pragma unroll
        for (int jj = 0; jj < 8; ++jj) {
            int jd = j0 + jj;
            float acc = b1[jd];
            #pragma unroll
            for (int k = 0; k < 7; ++k) acc += W1[jd * 7 + k] * m[k];
            hx[1][b][jd] = (bf16_t)fmaxf(acc, 0.f);
        }
    }
    __syncthreads();

    // ---- enc2 via MFMA: wave wv rows [64wv,64wv+64); rows<256 -> h0(hx[0]), >=256 -> c0(cbuf) ----
    float* cbuf = (float*)&wg[0][0];  // fp32 [256][17] staging inside wg space
    {
        f32x4 e[4] = {zero4, zero4, zero4, zero4};
        #pragma unroll
        for (int kk = 0; kk < 9; ++kk) {
            int ko = 32 * kk + 8 * quad;
            bf16x8 bf = *(const bf16x8*)&hx[1][l15][ko];
            #pragma unroll
            for (int m = 0; m < 4; ++m) {
                bf16x8 aa = *(const bf16x8*)&w2e[(size_t)(64 * wv + 16 * m + l15) * KEXT + ko];
                e[m] = MFMA16(aa, bf, e[m]);
            }
        }
        #pragma unroll
        for (int m = 0; m < 4; ++m) {
            int row = 64 * wv + 16 * m + 4 * quad;
            if (row < 256) {  // h0
                *(unsigned*)&hx[0][l15][row]     = pk2(fmaxf(e[m][0], 0.f), fmaxf(e[m][1], 0.f));
                *(unsigned*)&hx[0][l15][row + 2] = pk2(fmaxf(e[m][2], 0.f), fmaxf(e[m][3], 0.f));
            } else {          // c0
                int d = row - 256;
                #pragma unroll
                for (int r = 0; r < 4; ++r)
                    cbuf[(size_t)(d + r) * 17 + l15] = fmaxf(e[m][r], 0.f);
            }
        }
    }
    __syncthreads();

    // ---- c0 -> regs: c[half][r] at dim 32wv+16half+4quad+r, batch l15 ----
    f32x4 c[2];
    #pragma unroll
    for (int half = 0; half < 2; ++half)
        #pragma unroll
        for (int r = 0; r < 4; ++r)
            c[half][r] = cbuf[(size_t)(32 * wv + 16 * half + 4 * quad + r) * 17 + l15];
    __syncthreads();

    // ---- gate g -> LDS (overwrites cbuf); Wo2 -> LDS ----
    #pragma unroll
    for (int i = 0; i < 17; ++i) {
        int idx = tid + 512 * i;
        if (idx < 256 * 33) {
            int r = idx / 33, c8 = idx - r * 33;
            *(bf16x8*)&wg[r][8 * c8] = *(const bf16x8*)&wall[(size_t)(512 + r) * KEXT + 8 * c8];
        }
    }
    #pragma unroll
    for (int i = 0; i < 4; ++i) {
        int idx = tid + 512 * i;
        int r = idx >> 7, cc = idx & 127;
        wo2l[r][cc] = wo2e[r * 128 + cc];
    }

    // ---- resident A-frags: gates i,f for dims [32wv,32wv+32): af[g][half][kk] = 144 VGPR ----
    bf16x8 af[2][2][9];
    #pragma unroll
    for (int g = 0; g < 2; ++g)
        #pragma unroll
        for (int h = 0; h < 2; ++h)
            #pragma unroll
            for (int kk = 0; kk < 9; ++kk)
                af[g][h][kk] = *(const bf16x8*)&wall[(size_t)(256 * g + 32 * wv + 16 * h + l15) * KEXT
                                                     + 32 * kk + 8 * quad];

    // ---- stream bases (t-invariant addresses) ----
    const bf16_t* obase = wall + (size_t)(768  + 32 * wv + l15) * KEXT + 8 * quad;  // gate o
    const bf16_t* wbase = wall + (size_t)(1024 + 16 * wv + l15) * KEXT + 8 * quad;  // Wo1

    const float bo2v0 = bo2[0], bo2v1 = bo2[1], bo2v2 = bo2[2];

    // ---- rings (carried across iterations): fill slots 0,1 once ----
    bf16x8 ob[3][2], wr[3];
    #pragma unroll
    for (int s = 0; s < 2; ++s) {
        wr[s] = *(const bf16x8*)(wbase + 32 * s);
        #pragma unroll
        for (int h = 0; h < 2; ++h)
            ob[s][h] = *(const bf16x8*)(obase + (size_t)(16 * h) * KEXT + 32 * s);
    }

    // ---- x_0 fragment in regs: quad0 = {m0,m1,m2,1,0..}, quads 1..3 = 0 ----
    bf16x8 xf;
    #pragma unroll
    for (int j = 0; j < 8; ++j) xf[j] = (bf16_t)0.f;
    if (quad == 0) {
        xf[0] = (bf16_t)meta[(size_t)(gb + l15) * 7 + 0];
        xf[1] = (bf16_t)meta[(size_t)(gb + l15) * 7 + 1];
        xf[2] = (bf16_t)meta[(size_t)(gb + l15) * 7 + 2];
        xf[3] = (bf16_t)1.f;
    }

    __syncthreads();   // wg/wo2l ready (one-time full sync is fine here)

    // ================= time loop: G (gates+cell) -> B1 -> Z -> B2 -> Y (no barrier) ======
    for (int i = 0; i < TSTEPS; ++i) {
        const bf16_t (*cur)[HS] = hx[i & 1];         // h_i
        bf16_t (*nxt)[HS]       = hx[(i + 1) & 1];   // h_{i+1} destination

        // -- G: gates_i = [h_i|x_i|1] @ Wall^T; kk<8 B from LDS, kk=8 B = xf regs.
        //       o-ring: consume ob[kk%3] (slice kk), load slice (kk+2)%9 -> slot (kk+2)%3 --
        f32x4 acc[4][2];
        #pragma unroll
        for (int g = 0; g < 4; ++g) { acc[g][0] = zero4; acc[g][1] = zero4; }

        #pragma unroll
        for (int kk = 0; kk < 9; ++kk) {
            int ko = 32 * kk + 8 * quad;
            bf16x8 bf = (kk < 8) ? *(const bf16x8*)&cur[l15][ko] : xf;
            #pragma unroll
            for (int h = 0; h < 2; ++h)
                ob[(kk + 2) % 3][h] = *(const bf16x8*)(obase + (size_t)(16 * h) * KEXT
                                                       + 32 * ((kk + 2) % 9));
            #pragma unroll
            for (int h = 0; h < 2; ++h) {
                // kk=8: wg read past col 263 aliases next row's cols; B is zero there -> harmless
                bf16x8 ag = *(const bf16x8*)&wg[32 * wv + 16 * h + l15][ko];
                acc[0][h] = MFMA16(af[0][h][kk], bf, acc[0][h]);
                acc[1][h] = MFMA16(af[1][h][kk], bf, acc[1][h]);
                acc[2][h] = MFMA16(ag,            bf, acc[2][h]);
                acc[3][h] = MFMA16(ob[kk % 3][h], bf, acc[3][h]);
            }
        }

        // -- cell update (regs) + write h_{i+1} --
        #pragma unroll
        for (int half = 0; half < 2; ++half) {
            float hh[4];
            #pragma unroll
            for (int r = 0; r < 4; ++r) {
                float iv = acc[0][half][r], fv = acc[1][half][r];
                float gv = acc[2][half][r], ov = acc[3][half][r];
                float cc = sigm(fv) * c[half][r] + sigm(iv) * tanh_f(gv);
                c[half][r] = cc;
                hh[r] = sigm(ov) * tanh_f(cc);
            }
            int dim = 32 * wv + 16 * half + 4 * quad;
            *(unsigned*)&nxt[l15][dim]     = pk2(hh[0], hh[1]);
            *(unsigned*)&nxt[l15][dim + 2] = pk2(hh[2], hh[3]);
        }
        bar_lds();   // B1: h_{i+1} visible; ring wrap loads stay in flight

        // -- Z: z_i = relu(h_{i+1} @ Wo1ext^T); wave wv -> z-dims [16wv,16wv+16).
        //       wr-ring: consume wr[kk%3] (slice kk), load slice (kk+2)%9 -> slot (kk+2)%3 --
        {
            f32x4 za = zero4;
            #pragma unroll
            for (int kk = 0; kk < 9; ++kk) {
                int ko = 32 * kk + 8 * quad;
                bf16x8 b = *(const bf16x8*)&nxt[l15][ko];   // ext cols: x*0 (Wo1ext=0), ones*bo1
                za = MFMA16(wr[kk % 3], b, za);
                wr[(kk + 2) % 3] = *(const bf16x8*)(wbase + 32 * ((kk + 2) % 9));
            }
            int zd = 16 * wv + 4 * quad;
            *(unsigned*)&zbuf[l15][zd]     = pk2(fmaxf(za[0], 0.f), fmaxf(za[1], 0.f));
            *(unsigned*)&zbuf[l15][zd + 2] = pk2(fmaxf(za[2], 0.f), fmaxf(za[3], 0.f));
        }
        bar_lds();   // B2: z complete

        // -- Y: ALL waves redundantly y_i = z @ Wo2ext^T; xf <- x_{i+1}; rotate out-store.
        //       No trailing barrier (Y touches only zbuf/wo2l; hazards covered by B1/B2) --
        {
            f32x4 ya = zero4;
            #pragma unroll
            for (int kk = 0; kk < 4; ++kk) {
                int ko = 32 * kk + 8 * quad;
                ya = MFMA16(*(const bf16x8*)&wo2l[l15][ko],
                            *(const bf16x8*)&zbuf[l15][ko], ya);
            }
            float y0 = ya[0] + bo2v0, y1 = ya[1] + bo2v1, y2 = ya[2] + bo2v2;
            if (wv == (i & 7) && quad == 0) {   // rotate storer: ack never blocks a barrier
                float* op = out + ((size_t)(gb + l15) * TSTEPS + i) * 3;
                op[0] = y0; op[1] = y1; op[2] = y2;
            }
            if (quad == 0) {
                xf[0] = (bf16_t)y0; xf[1] = (bf16_t)y1; xf[2] = (bf16_t)y2; xf[3] = (bf16_t)1.f;
            }
        }
    }
}

extern "C" void kernel_launch(void* const* d_in, const int* in_sizes, int n_in,
                              void* d_out, int out_size, void* d_ws, size_t ws_size,
                              hipStream_t stream)
{
    const float* meta = (const float*)d_in[0];
    const float* W1   = (const float*)d_in[2];
    const float* b1   = (const float*)d_in[3];
    const float* W2   = (const float*)d_in[4];
    const float* b2   = (const float*)d_in[5];
    const float* Wih  = (const float*)d_in[6];
    const float* Whh  = (const float*)d_in[7];
    const float* bih  = (const float*)d_in[8];
    const float* bhh  = (const float*)d_in[9];
    const float* Wo1  = (const float*)d_in[10];
    const float* bo1  = (const float*)d_in[11];
    const float* Wo2  = (const float*)d_in[12];
    const float* bo2  = (const float*)d_in[13];
    bf16_t* ws  = (bf16_t*)d_ws;
    float*  out = (float*)d_out;

    prep_kernel<<<dim3((WS_ELEMS + 255) / 256), dim3(256), 0, stream>>>(
        W2, b2, Wih, Whh, bih, bhh, Wo1, bo1, Wo2, ws);
    lstm_main<<<dim3(4096 / TILE_B), dim3(512), 0, stream>>>(
        meta, W1, b1, bo2, ws, out);
}